// Round 1
// baseline (274.105 us; speedup 1.0000x reference)
//
#include <hip/hip_runtime.h>
#include <math.h>

#define D 64
#define NI 100
#define BSZ 64
#define LN_EPS 1e-5f

// ws layout (floats):
#define OFF_PA   0
#define OFF_PB   (BSZ*NI*D)
#define OFF_W12T (2*BSZ*NI*D)
#define OFF_W3GT (OFF_W12T + 128*64)
#define OFF_W3G  (OFF_W3GT + 64*64)
#define OFF_W3B  (OFF_W3G + 64)

// K0: transpose w_ij into coalesced layouts, fold ln_g into w3, precompute w3*g, w3*b
__global__ void k0_prep(const float* __restrict__ w_ij,
                        const float* __restrict__ g,
                        const float* __restrict__ bln,
                        float* __restrict__ ws) {
  __shared__ float w_s[64 * 193];  // padded to kill bank conflicts on transposed reads
  int tid = threadIdx.x;
  for (int idx = tid; idx < 64 * 192; idx += 256) {
    int dd = idx / 192, k = idx - dd * 192;
    w_s[dd * 193 + k] = w_ij[idx];
  }
  __syncthreads();
  float* W12T = ws + OFF_W12T;
  float* W3GT = ws + OFF_W3GT;
  for (int idx = tid; idx < 128 * 64; idx += 256) {
    int k = idx >> 6, dd = idx & 63;
    W12T[idx] = w_s[dd * 193 + k];
  }
  for (int idx = tid; idx < 64 * 64; idx += 256) {
    int k = idx >> 6, dd = idx & 63;
    W3GT[idx] = w_s[dd * 193 + 128 + k] * g[k];
  }
  if (tid < 64) {
    float wg = 0.f, wb = 0.f;
#pragma unroll
    for (int k = 0; k < 64; ++k) {
      float w = w_s[tid * 193 + 128 + k];
      wg = fmaf(w, g[k], wg);
      wb = fmaf(w, bln[k], wb);
    }
    ws[OFF_W3G + tid] = wg;
    ws[OFF_W3B + tid] = wb;
  }
}

// K1: per-item layernorm + the two per-item projections Pa = w1*LN(e), Pb = w2*LN(e)
__global__ void k1_proj(const float* __restrict__ emb,
                        const float* __restrict__ g,
                        const float* __restrict__ bln,
                        float* __restrict__ ws) {
  int t = blockIdx.x;
  int lane = threadIdx.x;
  float e = emb[t * 64 + lane];
  float s = e, s2 = e * e;
#pragma unroll
  for (int off = 32; off > 0; off >>= 1) {
    s  += __shfl_xor(s, off, 64);
    s2 += __shfl_xor(s2, off, 64);
  }
  float mu  = s * (1.f / 64.f);
  float var = s2 * (1.f / 64.f) - mu * mu;
  float rs  = rsqrtf(var + LN_EPS);
  float lne = (e - mu) * rs * g[lane] + bln[lane];
  __shared__ float L[64];
  L[lane] = lne;
  __syncthreads();
  const float* W12T = ws + OFF_W12T;
  float p1 = 0.f, p2 = 0.f;
#pragma unroll
  for (int k = 0; k < 64; ++k) {
    float lk = L[k];
    p1 = fmaf(W12T[k * 64 + lane],        lk, p1);
    p2 = fmaf(W12T[(k + 64) * 64 + lane], lk, p2);
  }
  ws[OFF_PA + t * 64 + lane] = p1;
  ws[OFF_PB + t * 64 + lane] = p2;
}

// K2: one block per (b,i). 4 waves x 64 lanes (lane = output dim d' / feature k).
__global__ __launch_bounds__(256) void k2_main(
    const float* __restrict__ emb,
    const float* __restrict__ bij,
    const float* __restrict__ wsum,
    const float* __restrict__ bsum,
    const float* __restrict__ ws,
    float* __restrict__ out) {
  int bid = blockIdx.x;
  int b = bid / NI, i = bid - b * NI;
  int tid = threadIdx.x;
  int wave = tid >> 6, lane = tid & 63;

  __shared__ float EJ[NI * 64];     // 25.6 KB: all embeddings of batch b
  __shared__ float WT[64 * 64];     // 16 KB: W3gT[k][d']
  __shared__ float rs_s[NI], mrs_s[NI];
  __shared__ float zrow[NI];        // z, then alpha
  __shared__ float part[256];

  const float* eb = emb + b * NI * 64;
  for (int idx = tid; idx < NI * 16; idx += 256)
    ((float4*)EJ)[idx] = ((const float4*)eb)[idx];
  const float* W3GT = ws + OFF_W3GT;
  for (int idx = tid; idx < 1024; idx += 256)
    ((float4*)WT)[idx] = ((const float4*)W3GT)[idx];
  __syncthreads();

  // per-lane constants (lane = d' for phases 2-3)
  float w3g_l  = ws[OFF_W3G + lane];
  float w3b_l  = ws[OFF_W3B + lane];
  float bij_l  = bij[lane];
  float wsum_l = wsum[lane];
  float pb_l   = ws[OFF_PB + (b * NI + i) * 64 + lane];
  float bsum0  = bsum[0];
  float ei_l   = EJ[i * 64 + lane];   // lane = k here

  // phase 1: per-pair layernorm stats (v = e_i .* e_j), wave w owns j in [25w, 25w+25)
  for (int jj = 0; jj < 25; ++jj) {
    int j = wave * 25 + jj;
    float v = ei_l * EJ[j * 64 + lane];
    float s = v, s2 = v * v;
#pragma unroll
    for (int off = 32; off > 0; off >>= 1) {
      s  += __shfl_xor(s, off, 64);
      s2 += __shfl_xor(s2, off, 64);
    }
    if (lane == 0) {
      float mu  = s * (1.f / 64.f);
      float var = s2 * (1.f / 64.f) - mu * mu;
      float rs  = rsqrtf(var + LN_EPS);
      rs_s[j]  = rs;
      mrs_s[j] = mu * rs;
    }
  }

  // phase 2: register-resident column of M_i: mt[k] = W3g[d'=lane][k] * e_i[k]
  float mt[64];
#pragma unroll
  for (int k = 0; k < 64; ++k)
    mt[k] = WT[k * 64 + lane] * EJ[i * 64 + k];

  __syncthreads();

  // phase 3: q = M_i . e_j, then att = tanh(...), z_j = <att, wsum>
  for (int jj = 0; jj < 25; ++jj) {
    int j = wave * 25 + jj;
    float q = 0.f;
    const float4* ej4 = (const float4*)&EJ[j * 64];
#pragma unroll
    for (int k4 = 0; k4 < 16; ++k4) {
      float4 e4 = ej4[k4];
      q = fmaf(mt[4 * k4 + 0], e4.x, q);
      q = fmaf(mt[4 * k4 + 1], e4.y, q);
      q = fmaf(mt[4 * k4 + 2], e4.z, q);
      q = fmaf(mt[4 * k4 + 3], e4.w, q);
    }
    float t3 = rs_s[j] * q - mrs_s[j] * w3g_l + w3b_l;
    float pa = ws[OFF_PA + (b * NI + j) * 64 + lane];
    float x  = pa + pb_l + t3 + bij_l;
    // tanh(x) = 1 - 2/(exp(2x)+1)
    float e2x = __expf(2.f * x);
    float th  = 1.f - 2.f / (e2x + 1.f);
    float zl  = th * wsum_l;
#pragma unroll
    for (int off = 32; off > 0; off >>= 1)
      zl += __shfl_xor(zl, off, 64);
    if (lane == 0)
      zrow[j] = (j == i) ? -__builtin_inff() : (zl + bsum0);
  }
  __syncthreads();

  // phase 4: softmax over j (wave 0; lanes cover j and j+64)
  if (wave == 0) {
    float z0 = zrow[lane];
    float z1 = (lane + 64 < NI) ? zrow[lane + 64] : -__builtin_inff();
    float m = fmaxf(z0, z1);
#pragma unroll
    for (int off = 32; off > 0; off >>= 1)
      m = fmaxf(m, __shfl_xor(m, off, 64));
    float e0 = __expf(z0 - m);
    float e1 = (lane + 64 < NI) ? __expf(z1 - m) : 0.f;
    float ssum = e0 + e1;
#pragma unroll
    for (int off = 32; off > 0; off >>= 1)
      ssum += __shfl_xor(ssum, off, 64);
    float inv = 1.f / ssum;
    zrow[lane] = e0 * inv;
    if (lane + 64 < NI) zrow[lane + 64] = e1 * inv;
  }
  __syncthreads();

  // phase 5: ctx_k = e_i[k] * sum_j alpha_j e_j[k] + e_i[k]^2, leaky relu
  float acc = 0.f;
  for (int jj = 0; jj < 25; ++jj) {
    int j = wave * 25 + jj;
    acc = fmaf(zrow[j], EJ[j * 64 + lane], acc);
  }
  part[wave * 64 + lane] = acc;
  __syncthreads();
  if (wave == 0) {
    float ssum = part[lane] + part[64 + lane] + part[128 + lane] + part[192 + lane];
    float c = fmaf(ei_l, ssum, ei_l * ei_l);
    c = (c >= 0.f) ? c : 0.01f * c;
    out[(b * NI + i) * 64 + lane] = c;
  }
}

extern "C" void kernel_launch(void* const* d_in, const int* in_sizes, int n_in,
                              void* d_out, int out_size, void* d_ws, size_t ws_size,
                              hipStream_t stream) {
  const float* emb  = (const float*)d_in[0];
  const float* g    = (const float*)d_in[1];
  const float* bln  = (const float*)d_in[2];
  const float* w_ij = (const float*)d_in[3];
  const float* bij  = (const float*)d_in[4];
  const float* wsum = (const float*)d_in[5];
  const float* bsum = (const float*)d_in[6];
  float* ws  = (float*)d_ws;
  float* out = (float*)d_out;

  hipLaunchKernelGGL(k0_prep, dim3(1), dim3(256), 0, stream, w_ij, g, bln, ws);
  hipLaunchKernelGGL(k1_proj, dim3(BSZ * NI), dim3(64), 0, stream, emb, g, bln, ws);
  hipLaunchKernelGGL(k2_main, dim3(BSZ * NI), dim3(256), 0, stream,
                     emb, bij, wsum, bsum, ws, out);
}

// Round 2
// 89.746 us; speedup vs baseline: 3.0542x; 3.0542x over previous
//
#include <hip/hip_runtime.h>
#include <math.h>

#define D 64
#define NI 100
#define BSZ 64
#define LN_EPS 1e-5f

// ws layout (floats):
#define OFF_PA    0
#define OFF_PB    (BSZ*NI*D)
#define OFF_W12T  (2*BSZ*NI*D)
#define OFF_W3GTT (OFF_W12T + 128*64)
#define OFF_W3G   (OFF_W3GTT + 64*64)
#define OFF_W3B   (OFF_W3G + 64)

typedef __attribute__((ext_vector_type(8))) short bf8;
typedef __attribute__((ext_vector_type(4))) float f32x4;

__device__ inline uint32_t f2bf(float x) {
  uint32_t u = __float_as_uint(x);
  return (u + 0x7fffu + ((u >> 16) & 1u)) >> 16;
}
__device__ inline float bf2f(uint32_t h) { return __uint_as_float(h << 16); }
__device__ inline int pk2(float a, float b) { return (int)(f2bf(a) | (f2bf(b) << 16)); }

__device__ inline bf8 sq8(bf8 a) {
  bf8 r;
#pragma unroll
  for (int t = 0; t < 8; ++t) {
    float v = bf2f((uint32_t)(unsigned short)a[t]);
    r[t] = (short)f2bf(v * v);
  }
  return r;
}

// K0: build W12T (k-major for k1), W3GTT[d][k]=w3[d,k]*g[k] (d-major, fp32),
// and the folded vectors w3g_dot[d], w3b_dot[d].
__global__ void k0_prep(const float* __restrict__ w_ij,
                        const float* __restrict__ g,
                        const float* __restrict__ bln,
                        float* __restrict__ ws) {
  __shared__ float w_s[64 * 193];
  int tid = threadIdx.x;
  for (int idx = tid; idx < 64 * 192; idx += 256) {
    int dd = idx / 192, k = idx - dd * 192;
    w_s[dd * 193 + k] = w_ij[idx];
  }
  __syncthreads();
  float* W12T = ws + OFF_W12T;
  float* W3GTT = ws + OFF_W3GTT;
  for (int idx = tid; idx < 128 * 64; idx += 256) {
    int k = idx >> 6, dd = idx & 63;
    W12T[idx] = w_s[dd * 193 + k];
  }
  for (int idx = tid; idx < 64 * 64; idx += 256) {
    int dd = idx >> 6, k = idx & 63;
    W3GTT[idx] = w_s[dd * 193 + 128 + k] * g[k];
  }
  if (tid < 64) {
    float wg = 0.f, wb = 0.f;
#pragma unroll
    for (int k = 0; k < 64; ++k) {
      float w = w_s[tid * 193 + 128 + k];
      wg = fmaf(w, g[k], wg);
      wb = fmaf(w, bln[k], wb);
    }
    ws[OFF_W3G + tid] = wg;
    ws[OFF_W3B + tid] = wb;
  }
}

// K1: per-item LN + per-item projections Pa = w1*LN(e), Pb = w2*LN(e)
__global__ void k1_proj(const float* __restrict__ emb,
                        const float* __restrict__ g,
                        const float* __restrict__ bln,
                        float* __restrict__ ws) {
  int t = blockIdx.x;
  int lane = threadIdx.x;
  float e = emb[t * 64 + lane];
  float s = e, s2 = e * e;
#pragma unroll
  for (int off = 32; off > 0; off >>= 1) {
    s  += __shfl_xor(s, off, 64);
    s2 += __shfl_xor(s2, off, 64);
  }
  float mu  = s * (1.f / 64.f);
  float var = s2 * (1.f / 64.f) - mu * mu;
  float rs  = rsqrtf(var + LN_EPS);
  float lne = (e - mu) * rs * g[lane] + bln[lane];
  __shared__ float L[64];
  L[lane] = lne;
  __syncthreads();
  const float* W12T = ws + OFF_W12T;
  float p1 = 0.f, p2 = 0.f;
#pragma unroll
  for (int k = 0; k < 64; ++k) {
    float lk = L[k];
    p1 = fmaf(W12T[k * 64 + lane],        lk, p1);
    p2 = fmaf(W12T[(k + 64) * 64 + lane], lk, p2);
  }
  ws[OFF_PA + t * 64 + lane] = p1;
  ws[OFF_PB + t * 64 + lane] = p2;
}

// K2: one block per (b,i); 4 waves. MFMA 16x16x32_bf16.
// A = E_b (128x64 padded, bf16, XOR-swizzled LDS). B = MT (80x64: rows d'=0..63
// hold M_i^T[d'][k]=e_i[k]*w3g[k][d']; row 64 = e_i; row 65 = e_i^2).
// Wave w owns M-tiles {w, w+4}, all N-tiles.
__global__ __launch_bounds__(256, 3) void k2_main(
    const float* __restrict__ emb,
    const float* __restrict__ bij,
    const float* __restrict__ wsum,
    const float* __restrict__ bsum,
    const float* __restrict__ ws,
    float* __restrict__ out) {
  int bid = blockIdx.x;
  int b = bid / NI, i = bid - b * NI;
  int tid = threadIdx.x;
  int wv = tid >> 6, lane = tid & 63, g = lane >> 4, c = lane & 15;

  __shared__ ushort E16[128 * 64];  // 16 KB, swizzled
  __shared__ ushort MT[80 * 64];    // 10 KB, swizzled
  __shared__ float z_s[128];
  __shared__ float part[256];

  const float* eb = emb + b * NI * D;
  const float* eirow = emb + (b * NI + i) * D;

  // stage E16 (bf16, rows >= NI zero), swizzle byte ^= ((row&7)<<4)
  for (int cc = tid; cc < 1024; cc += 256) {
    int r = cc >> 3, cb = cc & 7;
    int4 pkv;
    if (r < NI) {
      const float* s = eb + r * D + cb * 8;
      float4 f0 = *(const float4*)s, f1 = *(const float4*)(s + 4);
      pkv.x = pk2(f0.x, f0.y); pkv.y = pk2(f0.z, f0.w);
      pkv.z = pk2(f1.x, f1.y); pkv.w = pk2(f1.z, f1.w);
    } else {
      pkv = make_int4(0, 0, 0, 0);
    }
    int byte = r * 128 + cb * 16;
    *(int4*)((char*)E16 + (byte ^ ((r & 7) << 4))) = pkv;
  }
  // stage MT
  const float* W3 = ws + OFF_W3GTT;
  for (int cc = tid; cc < 640; cc += 256) {
    int r = cc >> 3, cb = cc & 7, k0 = cb * 8;
    int4 pkv;
    if (r < 64) {
      const float* wp = W3 + r * 64 + k0;
      float4 w0 = *(const float4*)wp, w1 = *(const float4*)(wp + 4);
      float4 e0 = *(const float4*)(eirow + k0), e1 = *(const float4*)(eirow + k0 + 4);
      pkv.x = pk2(w0.x * e0.x, w0.y * e0.y); pkv.y = pk2(w0.z * e0.z, w0.w * e0.w);
      pkv.z = pk2(w1.x * e1.x, w1.y * e1.y); pkv.w = pk2(w1.z * e1.z, w1.w * e1.w);
    } else if (r == 64) {
      float4 e0 = *(const float4*)(eirow + k0), e1 = *(const float4*)(eirow + k0 + 4);
      pkv.x = pk2(e0.x, e0.y); pkv.y = pk2(e0.z, e0.w);
      pkv.z = pk2(e1.x, e1.y); pkv.w = pk2(e1.z, e1.w);
    } else if (r == 65) {
      float4 e0 = *(const float4*)(eirow + k0), e1 = *(const float4*)(eirow + k0 + 4);
      pkv.x = pk2(e0.x * e0.x, e0.y * e0.y); pkv.y = pk2(e0.z * e0.z, e0.w * e0.w);
      pkv.z = pk2(e1.x * e1.x, e1.y * e1.y); pkv.w = pk2(e1.z * e1.z, e1.w * e1.w);
    } else {
      pkv = make_int4(0, 0, 0, 0);
    }
    int byte = r * 128 + cb * 16;
    *(int4*)((char*)MT + (byte ^ ((r & 7) << 4))) = pkv;
  }

  // per-lane epilogue constants (d = 16n + c)
  float w3g_n[4], cst_n[4], wsum_n[4];
#pragma unroll
  for (int n = 0; n < 4; ++n) {
    int d = 16 * n + c;
    w3g_n[n]  = ws[OFF_W3G + d];
    cst_n[n]  = ws[OFF_PB + (b * NI + i) * 64 + d] + bij[d] + ws[OFF_W3B + d];
    wsum_n[n] = wsum[d];
  }
  float bsum0 = bsum[0];

  __syncthreads();

  f32x4 accQ[2][4], accS1[2], accS2[2];
#pragma unroll
  for (int mm = 0; mm < 2; ++mm) {
#pragma unroll
    for (int n = 0; n < 4; ++n) accQ[mm][n] = (f32x4)0.f;
    accS1[mm] = (f32x4)0.f;
    accS2[mm] = (f32x4)0.f;
  }

#pragma unroll
  for (int s = 0; s < 2; ++s) {
    bf8 a[2], asq[2];
#pragma unroll
    for (int mm = 0; mm < 2; ++mm) {
      int r = 16 * (wv + 4 * mm) + c;
      int byte = r * 128 + 16 * g + 64 * s;
      a[mm] = *(bf8*)((char*)E16 + (byte ^ ((r & 7) << 4)));
      asq[mm] = sq8(a[mm]);
    }
    bf8 bf_[5];
#pragma unroll
    for (int n = 0; n < 5; ++n) {
      int r = 16 * n + c;
      int byte = r * 128 + 16 * g + 64 * s;
      bf_[n] = *(bf8*)((char*)MT + (byte ^ ((r & 7) << 4)));
    }
#pragma unroll
    for (int mm = 0; mm < 2; ++mm) {
#pragma unroll
      for (int n = 0; n < 4; ++n)
        accQ[mm][n] = __builtin_amdgcn_mfma_f32_16x16x32_bf16(a[mm], bf_[n], accQ[mm][n], 0, 0, 0);
      accS1[mm] = __builtin_amdgcn_mfma_f32_16x16x32_bf16(a[mm],  bf_[4], accS1[mm], 0, 0, 0);
      accS2[mm] = __builtin_amdgcn_mfma_f32_16x16x32_bf16(asq[mm], bf_[4], accS2[mm], 0, 0, 0);
    }
  }

  // epilogue: x -> tanh -> z, per wave over its 2 M-tiles
#pragma unroll
  for (int mm = 0; mm < 2; ++mm) {
    int m = wv + 4 * mm;
    float rs[4], murs[4];
#pragma unroll
    for (int reg = 0; reg < 4; ++reg) {
      float s1 = __shfl(accS1[mm][reg], (lane & 48), 64);       // col 64: sum e_j*e_i
      float s2 = __shfl(accS2[mm][reg], (lane & 48) | 1, 64);   // col 65: sum e_j^2*e_i^2
      float muv = s1 * (1.f / 64.f);
      float ev2 = s2 * (1.f / 64.f);
      float var = ev2 - muv * muv;
      float r = rsqrtf(var + LN_EPS);
      rs[reg] = r;
      murs[reg] = muv * r;
    }
    float zacc[4] = {0.f, 0.f, 0.f, 0.f};
#pragma unroll
    for (int n = 0; n < 4; ++n) {
#pragma unroll
      for (int reg = 0; reg < 4; ++reg) {
        int j = 16 * m + 4 * g + reg;
        float pa = ws[OFF_PA + (b * NI + j) * 64 + (16 * n + c)];
        float x = pa + cst_n[n] + rs[reg] * accQ[mm][n][reg] - murs[reg] * w3g_n[n];
        float e2x = __expf(2.f * x);
        float th = 1.f - 2.f / (e2x + 1.f);
        zacc[reg] = fmaf(th, wsum_n[n], zacc[reg]);
      }
    }
#pragma unroll
    for (int reg = 0; reg < 4; ++reg) {
      float zv = zacc[reg];
      zv += __shfl_xor(zv, 1, 64);
      zv += __shfl_xor(zv, 2, 64);
      zv += __shfl_xor(zv, 4, 64);
      zv += __shfl_xor(zv, 8, 64);
      if (c == 0) z_s[16 * m + 4 * g + reg] = zv + bsum0;
    }
  }
  __syncthreads();

  // softmax over j (wave 0; 128 padded entries)
  if (wv == 0) {
    int j1 = lane + 64;
    float z0 = (lane == i) ? -__builtin_inff() : z_s[lane];
    float z1 = (j1 >= NI || j1 == i) ? -__builtin_inff() : z_s[j1];
    float m = fmaxf(z0, z1);
#pragma unroll
    for (int off = 32; off > 0; off >>= 1)
      m = fmaxf(m, __shfl_xor(m, off, 64));
    float e0 = __expf(z0 - m);
    float e1 = (j1 >= NI || j1 == i) ? 0.f : __expf(z1 - m);
    float ssum = e0 + e1;
#pragma unroll
    for (int off = 32; off > 0; off >>= 1)
      ssum += __shfl_xor(ssum, off, 64);
    float inv = 1.f / ssum;
    z_s[lane] = e0 * inv;
    z_s[j1] = e1 * inv;
  }
  __syncthreads();

  // PV: ctx_k = e_i[k] * sum_j alpha_j e_j[k] + e_i[k]^2, leaky relu
  float pv = 0.f;
  for (int jj = 0; jj < 25; ++jj) {
    int j = wv * 25 + jj;
    float aj = z_s[j];
    int byte = j * 128 + 2 * lane;
    ushort ev = *(ushort*)((char*)E16 + (byte ^ ((j & 7) << 4)));
    pv = fmaf(aj, bf2f(ev), pv);
  }
  part[wv * 64 + lane] = pv;
  __syncthreads();
  if (wv == 0) {
    float ssum = part[lane] + part[64 + lane] + part[128 + lane] + part[192 + lane];
    float eif = emb[(b * NI + i) * 64 + lane];
    float ctx = fmaf(eif, ssum, eif * eif);
    ctx = (ctx >= 0.f) ? ctx : 0.01f * ctx;
    out[(b * NI + i) * 64 + lane] = ctx;
  }
}

extern "C" void kernel_launch(void* const* d_in, const int* in_sizes, int n_in,
                              void* d_out, int out_size, void* d_ws, size_t ws_size,
                              hipStream_t stream) {
  const float* emb  = (const float*)d_in[0];
  const float* g    = (const float*)d_in[1];
  const float* bln  = (const float*)d_in[2];
  const float* w_ij = (const float*)d_in[3];
  const float* bij  = (const float*)d_in[4];
  const float* wsum = (const float*)d_in[5];
  const float* bsum = (const float*)d_in[6];
  float* ws  = (float*)d_ws;
  float* out = (float*)d_out;

  hipLaunchKernelGGL(k0_prep, dim3(1), dim3(256), 0, stream, w_ij, g, bln, ws);
  hipLaunchKernelGGL(k1_proj, dim3(BSZ * NI), dim3(64), 0, stream, emb, g, bln, ws);
  hipLaunchKernelGGL(k2_main, dim3(BSZ * NI), dim3(256), 0, stream,
                     emb, bij, wsum, bsum, ws, out);
}

// Round 3
// 63.125 us; speedup vs baseline: 4.3423x; 1.4217x over previous
//
#include <hip/hip_runtime.h>
#include <math.h>

#define D 64
#define NI 100
#define BSZ 64
#define LN_EPS 1e-5f
#define NIP 112            // padded j rows (7 tiles of 16)
#define IT 4               // i's per block
#define NT2 25             // i-tiles per batch

// ws layout (floats):
#define OFF_PA    0
#define OFF_PB    (BSZ*NI*D)
#define OFF_W12T  (2*BSZ*NI*D)
#define OFF_W3GTT (OFF_W12T + 128*64)
#define OFF_W3G   (OFF_W3GTT + 64*64)
#define OFF_W3B   (OFF_W3G + 64)
#define OFF_WSUMS (OFF_W3B + 64)

typedef __attribute__((ext_vector_type(8))) short bf8;
typedef __attribute__((ext_vector_type(4))) float f32x4;

// truncating f32->bf16 pack (pair -> one dword): 3 ops
__device__ inline int pkt(float a, float b) {
  return (int)((__float_as_uint(a) >> 16) | (__float_as_uint(b) & 0xffff0000u));
}
// square a bf16x8 fragment, truncating round
__device__ inline bf8 sq8t(bf8 a) {
  bf8 r;
#pragma unroll
  for (int t = 0; t < 8; ++t) {
    float v = __uint_as_float(((uint32_t)(unsigned short)a[t]) << 16);
    r[t] = (short)(__float_as_uint(v * v) >> 16);
  }
  return r;
}

// K0: W12T (k-major), W3GTT[d][k]=w3[d,128+k]*g[k], folded dot vectors, sum(wsum)
__global__ void k0_prep(const float* __restrict__ w_ij,
                        const float* __restrict__ g,
                        const float* __restrict__ bln,
                        const float* __restrict__ wsum,
                        float* __restrict__ ws) {
  __shared__ float w_s[64 * 193];
  int tid = threadIdx.x;
  for (int idx = tid; idx < 64 * 192; idx += 256) {
    int dd = idx / 192, k = idx - dd * 192;
    w_s[dd * 193 + k] = w_ij[idx];
  }
  __syncthreads();
  float* W12T = ws + OFF_W12T;
  float* W3GTT = ws + OFF_W3GTT;
  for (int idx = tid; idx < 128 * 64; idx += 256) {
    int k = idx >> 6, dd = idx & 63;
    W12T[idx] = w_s[dd * 193 + k];
  }
  for (int idx = tid; idx < 64 * 64; idx += 256) {
    int dd = idx >> 6, k = idx & 63;
    W3GTT[idx] = w_s[dd * 193 + 128 + k] * g[k];
  }
  if (tid < 64) {
    float wg = 0.f, wb = 0.f;
#pragma unroll
    for (int k = 0; k < 64; ++k) {
      float w = w_s[tid * 193 + 128 + k];
      wg = fmaf(w, g[k], wg);
      wb = fmaf(w, bln[k], wb);
    }
    ws[OFF_W3G + tid] = wg;
    ws[OFF_W3B + tid] = wb;
  }
  if (tid == 0) {
    float s = 0.f;
    for (int k = 0; k < 64; ++k) s += wsum[k];
    ws[OFF_WSUMS] = s;
  }
}

// K1: per-item LN + Pa = w1*LN(e), Pb = w2*LN(e)
__global__ void k1_proj(const float* __restrict__ emb,
                        const float* __restrict__ g,
                        const float* __restrict__ bln,
                        float* __restrict__ ws) {
  int t = blockIdx.x;
  int lane = threadIdx.x;
  float e = emb[t * 64 + lane];
  float s = e, s2 = e * e;
#pragma unroll
  for (int off = 32; off > 0; off >>= 1) {
    s  += __shfl_xor(s, off, 64);
    s2 += __shfl_xor(s2, off, 64);
  }
  float mu  = s * (1.f / 64.f);
  float var = s2 * (1.f / 64.f) - mu * mu;
  float rs  = rsqrtf(var + LN_EPS);
  float lne = (e - mu) * rs * g[lane] + bln[lane];
  __shared__ float L[64];
  L[lane] = lne;
  __syncthreads();
  const float* W12T = ws + OFF_W12T;
  float p1 = 0.f, p2 = 0.f;
#pragma unroll
  for (int k = 0; k < 64; ++k) {
    float lk = L[k];
    p1 = fmaf(W12T[k * 64 + lane],        lk, p1);
    p2 = fmaf(W12T[(k + 64) * 64 + lane], lk, p2);
  }
  ws[OFF_PA + t * 64 + lane] = p1;
  ws[OFF_PB + t * 64 + lane] = p2;
}

// K2: one block per (b, 4-i tile); wave wv owns i = i0+wv end-to-end.
__global__ __launch_bounds__(256, 3) void k2_main(
    const float* __restrict__ emb,
    const float* __restrict__ bij,
    const float* __restrict__ wsum,
    const float* __restrict__ bsum,
    const float* __restrict__ ws,
    float* __restrict__ out) {
  int bid = blockIdx.x;
  int b = bid / NT2, itile = bid - b * NT2;
  int i0 = itile * IT;
  int tid = threadIdx.x;
  int wv = tid >> 6, lane = tid & 63, g = lane >> 4, c = lane & 15;
  int i = i0 + wv;

  __shared__ ushort E16[NIP * 64];       // 14336 B, swizzled bf16 E_b
  __shared__ ushort MT[IT][64 * 64];     // 4 x 8192 B, swizzled M_i^T
  __shared__ float rs2_s[IT][NIP];       // 2*rs per (local i, j)
  __shared__ float mrs2_s[IT][NIP];      // -2*mu*rs
  __shared__ float z_s[IT][NIP];         // z then alpha

  // stage E16 (trunc bf16, rows >= NI zero), swizzle byte ^= ((row&7)<<4)
  const float* eb = emb + b * NI * D;
  for (int u = tid; u < NIP * 8; u += 256) {
    int r = u >> 3, cb = u & 7;
    int4 pk;
    if (r < NI) {
      const float* sp = eb + r * 64 + cb * 8;
      float4 f0 = *(const float4*)sp, f1 = *(const float4*)(sp + 4);
      pk.x = pkt(f0.x, f0.y); pk.y = pkt(f0.z, f0.w);
      pk.z = pkt(f1.x, f1.y); pk.w = pkt(f1.z, f1.w);
    } else {
      pk = make_int4(0, 0, 0, 0);
    }
    int byte = r * 128 + cb * 16;
    *(int4*)((char*)E16 + (byte ^ ((r & 7) << 4))) = pk;
  }

  // build MT[wv]: MT[d][k] = w3g[d][k] * e_i[k] (trunc bf16)
  {
    const float* w3 = ws + OFF_W3GTT;
    const float* ei = emb + (b * NI + i) * 64;
#pragma unroll
    for (int it2 = 0; it2 < 8; ++it2) {
      int u = it2 * 64 + lane;
      int dd = u >> 3, kc = u & 7, k0 = kc * 8;
      float4 w0 = *(const float4*)(w3 + dd * 64 + k0);
      float4 w1 = *(const float4*)(w3 + dd * 64 + k0 + 4);
      float4 e0 = *(const float4*)(ei + k0);
      float4 e1 = *(const float4*)(ei + k0 + 4);
      int4 pk;
      pk.x = pkt(w0.x * e0.x, w0.y * e0.y);
      pk.y = pkt(w0.z * e0.z, w0.w * e0.w);
      pk.z = pkt(w1.x * e1.x, w1.y * e1.y);
      pk.w = pkt(w1.z * e1.z, w1.w * e1.w);
      int byte = dd * 128 + kc * 16;
      *(int4*)((char*)MT[wv] + (byte ^ ((dd & 7) << 4))) = pk;
    }
  }
  __syncthreads();

  // ---- pass G: Gram stats. A-tile rows = i0+c (local i = row 0..3) ----
  {
    bf8 aI[2], aIsq[2];
#pragma unroll
    for (int s = 0; s < 2; ++s) {
      int r = i0 + c;
      int byte = r * 128 + 16 * g + 64 * s;
      aI[s] = *(bf8*)((char*)E16 + (byte ^ ((r & 7) << 4)));
      aIsq[s] = sq8t(aI[s]);
    }
    for (int jt = wv; jt < 7; jt += 4) {
      f32x4 g1 = (f32x4)0.f, g2 = (f32x4)0.f;
#pragma unroll
      for (int s = 0; s < 2; ++s) {
        int r = 16 * jt + c;
        int byte = r * 128 + 16 * g + 64 * s;
        bf8 aj = *(bf8*)((char*)E16 + (byte ^ ((r & 7) << 4)));
        bf8 ajs = sq8t(aj);
        g1 = __builtin_amdgcn_mfma_f32_16x16x32_bf16(aI[s],  aj,  g1, 0, 0, 0);
        g2 = __builtin_amdgcn_mfma_f32_16x16x32_bf16(aIsq[s], ajs, g2, 0, 0, 0);
      }
      if (g == 0) {
#pragma unroll
        for (int reg = 0; reg < 4; ++reg) {
          float mu  = g1[reg] * (1.f / 64.f);
          float v2  = g2[reg] * (1.f / 64.f);
          float var = v2 - mu * mu;
          float rsv = rsqrtf(var + LN_EPS);
          rs2_s[reg][16 * jt + c]  = 2.f * rsv;
          mrs2_s[reg][16 * jt + c] = -2.f * mu * rsv;
        }
      }
    }
  }
  __syncthreads();

  // ---- pass Q: per-wave GEMM + fused epilogue ----
  // hoist B fragments (wave's own MT)
  bf8 bf_[4][2];
#pragma unroll
  for (int n = 0; n < 4; ++n)
#pragma unroll
    for (int s = 0; s < 2; ++s) {
      int r = 16 * n + c;
      int byte = r * 128 + 16 * g + 64 * s;
      bf_[n][s] = *(bf8*)((char*)MT[wv] + (byte ^ ((r & 7) << 4)));
    }

  float w3g_n[4], cst2_n[4], wsum_n[4];
#pragma unroll
  for (int n = 0; n < 4; ++n) {
    int d = 16 * n + c;
    w3g_n[n]  = ws[OFF_W3G + d];
    cst2_n[n] = 2.f * (ws[OFF_PB + (b * NI + i) * 64 + d] + bij[d] + ws[OFF_W3B + d]);
    wsum_n[n] = wsum[d];
  }
  float zbase = ws[OFF_WSUMS] + bsum[0];

  for (int m = 0; m < 7; ++m) {
    f32x4 q[4];
#pragma unroll
    for (int n = 0; n < 4; ++n) q[n] = (f32x4)0.f;
#pragma unroll
    for (int s = 0; s < 2; ++s) {
      int r = 16 * m + c;
      int byte = r * 128 + 16 * g + 64 * s;
      bf8 a = *(bf8*)((char*)E16 + (byte ^ ((r & 7) << 4)));
#pragma unroll
      for (int n = 0; n < 4; ++n)
        q[n] = __builtin_amdgcn_mfma_f32_16x16x32_bf16(a, bf_[n][s], q[n], 0, 0, 0);
    }
    float rs2v[4], mrs2v[4];
#pragma unroll
    for (int reg = 0; reg < 4; ++reg) {
      rs2v[reg]  = rs2_s[wv][16 * m + 4 * g + reg];
      mrs2v[reg] = mrs2_s[wv][16 * m + 4 * g + reg];
    }
    float zacc[4] = {0.f, 0.f, 0.f, 0.f};
#pragma unroll
    for (int n = 0; n < 4; ++n) {
#pragma unroll
      for (int reg = 0; reg < 4; ++reg) {
        int j = 16 * m + 4 * g + reg;
        float pa = ws[OFF_PA + (b * NI + j) * 64 + 16 * n + c];
        float X = fmaf(rs2v[reg], q[n][reg],
                   fmaf(mrs2v[reg], w3g_n[n], fmaf(2.f, pa, cst2_n[n])));
        float e2x = __expf(X);                       // e^{2x}
        float rr = __builtin_amdgcn_rcpf(e2x + 1.f); // tanh = 1 - 2*rr
        zacc[reg] = fmaf(wsum_n[n], rr, zacc[reg]);
      }
    }
#pragma unroll
    for (int reg = 0; reg < 4; ++reg) {
      float zv = zacc[reg];
      zv += __shfl_xor(zv, 1, 64);
      zv += __shfl_xor(zv, 2, 64);
      zv += __shfl_xor(zv, 4, 64);
      zv += __shfl_xor(zv, 8, 64);
      if (c == 0)
        z_s[wv][16 * m + 4 * g + reg] = fmaf(-2.f, zv, zbase);
    }
  }

  // ---- softmax (per wave, own row) ----
  {
    int j0 = lane, j1 = lane + 64;
    bool v0 = (j0 != i);
    bool v1 = (j1 < NI) && (j1 != i);
    float z0 = z_s[wv][j0];
    float z1 = (j1 < NIP) ? z_s[wv][j1] : 0.f;
    z0 = v0 ? z0 : -__builtin_inff();
    z1 = v1 ? z1 : -__builtin_inff();
    float mx = fmaxf(z0, z1);
#pragma unroll
    for (int off = 32; off > 0; off >>= 1)
      mx = fmaxf(mx, __shfl_xor(mx, off, 64));
    float e0 = v0 ? __expf(z0 - mx) : 0.f;
    float e1 = v1 ? __expf(z1 - mx) : 0.f;
    float ss = e0 + e1;
#pragma unroll
    for (int off = 32; off > 0; off >>= 1)
      ss += __shfl_xor(ss, off, 64);
    float inv = 1.f / ss;
    z_s[wv][j0] = e0 * inv;
    if (j1 < NIP) z_s[wv][j1] = e1 * inv;
  }

  // ---- PV: lane = (k-pair, j-half); ctx = leaky(e_i*sum + e_i^2) ----
  {
    int kp = lane & 31, half = lane >> 5;
    float s0 = 0.f, s1 = 0.f;
    int jb = half * 50;
    for (int t = 0; t < 50; ++t) {
      int j = jb + t;
      float al = z_s[wv][j];
      int byte = j * 128 + kp * 4;
      uint32_t u = *(const uint32_t*)((const char*)E16 + (byte ^ ((j & 7) << 4)));
      s0 = fmaf(al, __uint_as_float(u << 16), s0);
      s1 = fmaf(al, __uint_as_float(u & 0xffff0000u), s1);
    }
    s0 += __shfl_xor(s0, 32, 64);
    s1 += __shfl_xor(s1, 32, 64);
    if (half == 0) {
      const float* ei = emb + (b * NI + i) * 64;
      float e0 = ei[2 * kp], e1 = ei[2 * kp + 1];
      float c0 = fmaf(e0, s0, e0 * e0);
      float c1 = fmaf(e1, s1, e1 * e1);
      c0 = (c0 >= 0.f) ? c0 : 0.01f * c0;
      c1 = (c1 >= 0.f) ? c1 : 0.01f * c1;
      float2 o; o.x = c0; o.y = c1;
      *(float2*)(out + (b * NI + i) * 64 + 2 * kp) = o;
    }
  }
}

extern "C" void kernel_launch(void* const* d_in, const int* in_sizes, int n_in,
                              void* d_out, int out_size, void* d_ws, size_t ws_size,
                              hipStream_t stream) {
  const float* emb  = (const float*)d_in[0];
  const float* g    = (const float*)d_in[1];
  const float* bln  = (const float*)d_in[2];
  const float* w_ij = (const float*)d_in[3];
  const float* bij  = (const float*)d_in[4];
  const float* wsum = (const float*)d_in[5];
  const float* bsum = (const float*)d_in[6];
  float* ws  = (float*)d_ws;
  float* out = (float*)d_out;

  hipLaunchKernelGGL(k0_prep, dim3(1), dim3(256), 0, stream, w_ij, g, bln, wsum, ws);
  hipLaunchKernelGGL(k1_proj, dim3(BSZ * NI), dim3(64), 0, stream, emb, g, bln, ws);
  hipLaunchKernelGGL(k2_main, dim3(BSZ * NT2), dim3(256), 0, stream,
                     emb, bij, wsum, bsum, ws, out);
}